// Round 2
// baseline (1072.248 us; speedup 1.0000x reference)
//
#include <hip/hip_runtime.h>

typedef unsigned short u16;
typedef unsigned int   u32;

#define L_SEQ    2048
#define D_MODEL  1024
#define D_STATE  128
#define D_INNER  2048
#define NHEADS   32
#define HEADDIM  64
#define CONV_DIM 2304
#define D_IN_PROJ 4384
#define EPSF     1e-5f

using frag  = __attribute__((ext_vector_type(8))) short;
using f32x4 = __attribute__((ext_vector_type(4))) float;
typedef __attribute__((ext_vector_type(8))) unsigned short u16x8;

__device__ __forceinline__ u16 f2bf(float f) {
  u32 u = __float_as_uint(f);
  return (u16)((u + 0x7fffu + ((u >> 16) & 1u)) >> 16);
}
__device__ __forceinline__ float bf2f(u16 u) {
  return __uint_as_float(((u32)u) << 16);
}
__device__ __forceinline__ void async16(const void* g, void* l) {
  __builtin_amdgcn_global_load_lds((const __attribute__((address_space(1))) u32*)g,
                                   (__attribute__((address_space(3))) u32*)l, 16, 0, 0);
}

// ---------------- zero helper (avoid hipMemsetAsync under graph capture) ----------------
__global__ __launch_bounds__(256) void k_zero(u16* __restrict__ p, int n4) {
  int i = blockIdx.x * 256 + threadIdx.x;
  if (i < n4) ((ushort4*)p)[i] = ushort4{0, 0, 0, 0};
}

// ---------------- fp32 -> bf16 convert ----------------
__global__ __launch_bounds__(256) void k_cvt(const float* __restrict__ in,
                                             u16* __restrict__ out, int n4) {
  int i = blockIdx.x * 256 + threadIdx.x;
  if (i < n4) {
    float4 v = ((const float4*)in)[i];
    ushort4 o;
    o.x = f2bf(v.x); o.y = f2bf(v.y); o.z = f2bf(v.z); o.w = f2bf(v.w);
    ((ushort4*)out)[i] = o;
  }
}

// ---------------- bf16 MFMA GEMM:  C[M][ldc] = A[M][K] * B[N][K]^T ----------------
// m97 structure: 128x128 tile, BK=32, linear LDS, global_load_lds width=16.
// BF16OUT=1: write bf16 (plus f32 side-copy of dt columns). BF16OUT=0: f32 + resid.
template <int BF16OUT>
__global__ __launch_bounds__(256) void k_gemm(const u16* __restrict__ A,
                                              const u16* __restrict__ B, int K,
                                              int Nvalid, int ldc,
                                              u16* __restrict__ Cb,
                                              float* __restrict__ Cf,
                                              const float* __restrict__ resid,
                                              float* __restrict__ Cdt) {
  __shared__ __attribute__((aligned(16))) u16 As[128 * 32];
  __shared__ __attribute__((aligned(16))) u16 Bs[128 * 32];
  const int tid = threadIdx.x;
  const int lane = tid & 63;
  const int wid = tid >> 6;
  const int wm = wid >> 1, wn = wid & 1;
  const int m0 = blockIdx.x * 128, n0 = blockIdx.y * 128;

  f32x4 acc[4][4];
#pragma unroll
  for (int i = 0; i < 4; ++i)
#pragma unroll
    for (int j = 0; j < 4; ++j) acc[i][j] = f32x4{0.f, 0.f, 0.f, 0.f};

  // staging: wave wid stages 1KB chunks {2*wid, 2*wid+1} of As and Bs, linear.
  const char* gA[2]; const char* gB[2]; char* lA[2]; char* lB[2];
#pragma unroll
  for (int j = 0; j < 2; ++j) {
    int base = (wid * 2 + j) * 1024;         // chunk byte base (wave-uniform)
    int p = base + lane * 16;                // this lane's byte within LDS
    int row = p >> 6;                        // 64B per LDS row (32 bf16)
    int colb = p & 63;
    gA[j] = (const char*)A + ((size_t)(m0 + row) * K) * 2 + colb;
    gB[j] = (const char*)B + ((size_t)(n0 + row) * K) * 2 + colb;
    lA[j] = (char*)As + base;                // HW adds lane*16
    lB[j] = (char*)Bs + base;
  }

  const int kg = (lane >> 4) * 16;        // byte offset of this lane's k-group
  const int rr = wm * 64 + (lane & 15);   // A row within tile
  const int cc = wn * 64 + (lane & 15);   // B row (= output col) within tile

  for (int k0 = 0; k0 < K; k0 += 32) {
    size_t kb = (size_t)k0 * 2;
    async16(gA[0] + kb, lA[0]);
    async16(gA[1] + kb, lA[1]);
    async16(gB[0] + kb, lB[0]);
    async16(gB[1] + kb, lB[1]);
    __syncthreads();
    frag af[4], bfr[4];
#pragma unroll
    for (int mi = 0; mi < 4; ++mi)
      af[mi] = *(const frag*)((const char*)As + (rr + mi * 16) * 64 + kg);
#pragma unroll
    for (int ni = 0; ni < 4; ++ni)
      bfr[ni] = *(const frag*)((const char*)Bs + (cc + ni * 16) * 64 + kg);
#pragma unroll
    for (int mi = 0; mi < 4; ++mi)
#pragma unroll
      for (int ni = 0; ni < 4; ++ni)
        acc[mi][ni] = __builtin_amdgcn_mfma_f32_16x16x32_bf16(af[mi], bfr[ni],
                                                              acc[mi][ni], 0, 0, 0);
    __syncthreads();
  }

  // epilogue: D row = (lane>>4)*4 + reg, col = lane&15  (verified m89/m91)
  const int er = (lane >> 4) * 4;
  const int ec = lane & 15;
#pragma unroll
  for (int mi = 0; mi < 4; ++mi) {
#pragma unroll
    for (int ni = 0; ni < 4; ++ni) {
      int col = n0 + wn * 64 + ni * 16 + ec;
      if (col < Nvalid) {
#pragma unroll
        for (int r = 0; r < 4; ++r) {
          int row = m0 + wm * 64 + mi * 16 + er + r;
          size_t off = (size_t)row * ldc + col;
          float v = acc[mi][ni][r];
          if (BF16OUT) {
            Cb[off] = f2bf(v);
            if (col >= D_INNER + CONV_DIM)   // f32 side-copy of dt_raw columns
              Cdt[(size_t)row * NHEADS + (col - D_INNER - CONV_DIM)] = v;
          } else {
            Cf[off] = v + resid[off];
          }
        }
      }
    }
  }
}

// ---------------- depthwise causal conv(4) + bias + silu (bf16 in/out) ----------------
__global__ __launch_bounds__(256) void k_conv(const u16* __restrict__ zxb,
                                              const float* __restrict__ cw,
                                              const float* __restrict__ cb,
                                              u16* __restrict__ xcb) {
  int row = blockIdx.x;          // b*L + l
  int l = row & (L_SEQ - 1);
  for (int c4 = threadIdx.x; c4 < CONV_DIM / 4; c4 += 256) {
    int c = c4 * 4;
    float4 w0 = ((const float4*)cw)[c + 0];
    float4 w1 = ((const float4*)cw)[c + 1];
    float4 w2 = ((const float4*)cw)[c + 2];
    float4 w3 = ((const float4*)cw)[c + 3];
    float4 bias = *(const float4*)(cb + c);
    float a0 = bias.x, a1 = bias.y, a2 = bias.z, a3 = bias.w;
#pragma unroll
    for (int k = 0; k < 4; ++k) {
      int lm = l - 3 + k;
      if (lm >= 0) {
        ushort4 xv = *(const ushort4*)(zxb + (size_t)(row - 3 + k) * D_IN_PROJ + D_INNER + c);
        a0 = fmaf(bf2f(xv.x), (&w0.x)[k], a0);
        a1 = fmaf(bf2f(xv.y), (&w1.x)[k], a1);
        a2 = fmaf(bf2f(xv.z), (&w2.x)[k], a2);
        a3 = fmaf(bf2f(xv.w), (&w3.x)[k], a3);
      }
    }
    ushort4 o;
    o.x = f2bf(a0 / (1.f + expf(-a0)));
    o.y = f2bf(a1 / (1.f + expf(-a1)));
    o.z = f2bf(a2 / (1.f + expf(-a2)));
    o.w = f2bf(a3 / (1.f + expf(-a3)));
    *(ushort4*)(xcb + (size_t)row * CONV_DIM + c) = o;
  }
}

// ---------------- dt = softplus(raw+bias) (f32 raw), dA = exp(dt*A); -> [b][h][l] ----------------
__global__ __launch_bounds__(256) void k_dt(const float* __restrict__ dtf,
                                            const float* __restrict__ dtb,
                                            const float* __restrict__ alog,
                                            float* __restrict__ dtv,
                                            float* __restrict__ dAv) {
  int idx = blockIdx.x * 256 + threadIdx.x;  // (b*L + l)*32 + h
  int h = idx & 31;
  int row = idx >> 5;
  int l = row & (L_SEQ - 1);
  int b = row >> 11;
  float raw = dtf[(size_t)row * NHEADS + h] + dtb[h];
  float dt = raw > 20.f ? raw : log1pf(expf(raw));
  float A = -expf(alog[h]);
  size_t o = ((size_t)(b * NHEADS + h)) * L_SEQ + l;
  dtv[o] = dt;
  dAv[o] = expf(dt * A);
}

// ---------------- sequential SSM scan (bf16 in, bf16 out) ----------------
// block = (b, h, phalf): state slice 32(p) x 128(n) in registers.
// 512 threads: pl = t>>4 (p row), ng = t&15 (8 n's each).
__global__ __launch_bounds__(512) void k_scan(const u16* __restrict__ xcb,
                                              const float* __restrict__ dtv,
                                              const float* __restrict__ dAv,
                                              u16* __restrict__ ysb) {
  int bid = blockIdx.x;
  int ph = bid & 1;
  int bh = bid >> 1;          // b*32 + h
  int h = bh & 31;
  int b = bh >> 5;
  int t = threadIdx.x;
  int pl = t >> 4;
  int ng = t & 15;

  const float* dtp = dtv + (size_t)bh * L_SEQ;
  const float* dAp = dAv + (size_t)bh * L_SEQ;
  const u16* xrow = xcb + (size_t)b * L_SEQ * CONV_DIM;
  const int xoff = h * HEADDIM + ph * 32 + pl;
  const int boff = D_INNER + ng * 8;
  const int coff = D_INNER + D_STATE + ng * 8;
  u16* yout = ysb + (size_t)b * L_SEQ * D_INNER + h * HEADDIM + ph * 32 + pl;

  float s[8];
#pragma unroll
  for (int i = 0; i < 8; ++i) s[i] = 0.f;

  // prefetch step 0
  float p_dt = dtp[0], p_dA = dAp[0];
  u16 p_x = xrow[xoff];
  u16x8 pB = *(const u16x8*)(xrow + boff);
  u16x8 pC = *(const u16x8*)(xrow + coff);

  for (int l = 0; l < L_SEQ; ++l) {
    float c_dt = p_dt, c_dA = p_dA;
    u16 cx = p_x;
    u16x8 cB = pB, cC = pC;
    if (l + 1 < L_SEQ) {
      const u16* nrow = xrow + (size_t)(l + 1) * CONV_DIM;
      p_dt = dtp[l + 1]; p_dA = dAp[l + 1];
      p_x = nrow[xoff];
      pB = *(const u16x8*)(nrow + boff);
      pC = *(const u16x8*)(nrow + coff);
    }
    float dtx = c_dt * bf2f(cx);
    float acc = 0.f;
#pragma unroll
    for (int i = 0; i < 8; ++i) {
      s[i] = fmaf(s[i], c_dA, dtx * bf2f(cB[i]));
      acc = fmaf(s[i], bf2f(cC[i]), acc);
    }
    acc += __shfl_xor(acc, 1);
    acc += __shfl_xor(acc, 2);
    acc += __shfl_xor(acc, 4);
    acc += __shfl_xor(acc, 8);
    if (ng == 0) yout[(size_t)l * D_INNER] = f2bf(acc);
  }
}

// ---------------- y = (ys + D*x_ssm)*silu(z), RMSNorm, -> bf16 ----------------
__global__ __launch_bounds__(256) void k_gate(const u16* __restrict__ ysb,
                                              const u16* __restrict__ xcb,
                                              const u16* __restrict__ zxb,
                                              const float* __restrict__ Dp,
                                              const float* __restrict__ nw,
                                              u16* __restrict__ yb) {
  int row = blockIdx.x;
  int t = threadIdx.x;
  int d0 = t * 8;
  float Dh = Dp[d0 >> 6];
  u16x8 ya = *(const u16x8*)(ysb + (size_t)row * D_INNER + d0);
  u16x8 xa = *(const u16x8*)(xcb + (size_t)row * CONV_DIM + d0);
  u16x8 za = *(const u16x8*)(zxb + (size_t)row * D_IN_PROJ + d0);
  float v[8];
  float ss = 0.f;
#pragma unroll
  for (int c = 0; c < 8; ++c) {
    float val = bf2f(ya[c]) + Dh * bf2f(xa[c]);
    float zz = bf2f(za[c]);
    val *= zz / (1.f + expf(-zz));
    v[c] = val;
    ss += val * val;
  }
  __shared__ float red[4];
#pragma unroll
  for (int off = 32; off; off >>= 1) ss += __shfl_xor(ss, off);
  if ((t & 63) == 0) red[t >> 6] = ss;
  __syncthreads();
  float tot = red[0] + red[1] + red[2] + red[3];
  float scale = rsqrtf(tot * (1.f / D_INNER) + EPSF);
  float4 w0 = *(const float4*)(nw + d0);
  float4 w1 = *(const float4*)(nw + d0 + 4);
  u16x8 o;
  o[0] = f2bf(v[0] * scale * w0.x);
  o[1] = f2bf(v[1] * scale * w0.y);
  o[2] = f2bf(v[2] * scale * w0.z);
  o[3] = f2bf(v[3] * scale * w0.w);
  o[4] = f2bf(v[4] * scale * w1.x);
  o[5] = f2bf(v[5] * scale * w1.y);
  o[6] = f2bf(v[6] * scale * w1.z);
  o[7] = f2bf(v[7] * scale * w1.w);
  *(u16x8*)(yb + (size_t)row * D_INNER + d0) = o;
}

// ---------------- final LayerNorm (in-place on d_out) ----------------
union F4 { float4 v; float f[4]; };
__global__ __launch_bounds__(256) void k_ln(float* __restrict__ io,
                                            const float* __restrict__ lw,
                                            const float* __restrict__ lb) {
  int row = blockIdx.x;
  int t = threadIdx.x;
  int d0 = t * 4;
  F4 v; v.v = *(const float4*)(io + (size_t)row * D_MODEL + d0);
  float s1 = v.f[0] + v.f[1] + v.f[2] + v.f[3];
  float s2 = v.f[0] * v.f[0] + v.f[1] * v.f[1] + v.f[2] * v.f[2] + v.f[3] * v.f[3];
  __shared__ float r1[4], r2[4];
#pragma unroll
  for (int off = 32; off; off >>= 1) {
    s1 += __shfl_xor(s1, off);
    s2 += __shfl_xor(s2, off);
  }
  if ((t & 63) == 0) { r1[t >> 6] = s1; r2[t >> 6] = s2; }
  __syncthreads();
  float S1 = r1[0] + r1[1] + r1[2] + r1[3];
  float S2 = r2[0] + r2[1] + r2[2] + r2[3];
  float mu = S1 * (1.f / D_MODEL);
  float var = S2 * (1.f / D_MODEL) - mu * mu;
  float inv = rsqrtf(var + EPSF);
  F4 w, bb, o;
  w.v = *(const float4*)(lw + d0);
  bb.v = *(const float4*)(lb + d0);
#pragma unroll
  for (int c = 0; c < 4; ++c) o.f[c] = (v.f[c] - mu) * inv * w.f[c] + bb.f[c];
  *(float4*)(io + (size_t)row * D_MODEL + d0) = o.v;
}

extern "C" void kernel_launch(void* const* d_in, const int* in_sizes, int n_in,
                              void* d_out, int out_size, void* d_ws, size_t ws_size,
                              hipStream_t stream) {
  const float* x    = (const float*)d_in[0];
  const float* w1   = (const float*)d_in[1];
  const float* cw   = (const float*)d_in[2];
  const float* cb   = (const float*)d_in[3];
  const float* dtb  = (const float*)d_in[4];
  const float* alog = (const float*)d_in[5];
  const float* Dp   = (const float*)d_in[6];
  const float* nw   = (const float*)d_in[7];
  const float* w2   = (const float*)d_in[8];
  const float* lw   = (const float*)d_in[9];
  const float* lb   = (const float*)d_in[10];
  float* out = (float*)d_out;
  char* ws = (char*)d_ws;

  // workspace layout (bytes)                               size
  u16*   xb  = (u16*)(ws + 0);            // 8192x1024 bf16  16,777,216
  u16*   w1b = (u16*)(ws + 16777216);     // 4480x1024 bf16   9,175,040
  u16*   w2b = (u16*)(ws + 25952256);     // 1024x2048 bf16   4,194,304
  u16*   zxb = (u16*)(ws + 30146560);     // 8192x4384 bf16  71,827,456
  u16*   xcb = (u16*)(ws + 101974016);    // 8192x2304 bf16  37,748,736
  float* dtf = (float*)(ws + 139722752);  // 8192x32 f32      1,048,576
  float* dtv = (float*)(ws + 140771328);  // 128x2048 f32     1,048,576
  float* dAv = (float*)(ws + 141819904);  // 128x2048 f32     1,048,576
  u16*   ysb = (u16*)(ws + 142868480);    // 8192x2048 bf16  33,554,432
  u16*   yb  = (u16*)(ws + 176422912);    // 8192x2048 bf16  33,554,432
  // total: 209,977,344 bytes (~200.3 MiB)
  if (ws_size < (size_t)209977344) return;  // diagnostic: clean fail if ws too small

  // zero the padded tail of W1 (rows 4384..4479): 96*1024 u16 = 24576 ushort4
  k_zero<<<96, 256, 0, stream>>>(w1b + (size_t)4384 * 1024, 24576);

  k_cvt<<<8192, 256, 0, stream>>>(x, xb, 2097152);
  k_cvt<<<4384, 256, 0, stream>>>(w1, w1b, 1122304);
  k_cvt<<<2048, 256, 0, stream>>>(w2, w2b, 524288);

  // in_proj: zx[8192][4384] = xb[8192][1024] @ w1b[4480][1024]^T  (bf16 out + f32 dt copy)
  k_gemm<1><<<dim3(64, 35), 256, 0, stream>>>(xb, w1b, 1024, 4384, 4384,
                                              zxb, nullptr, nullptr, dtf);

  k_conv<<<8192, 256, 0, stream>>>(zxb, cw, cb, xcb);
  k_dt<<<1024, 256, 0, stream>>>(dtf, dtb, alog, dtv, dAv);
  k_scan<<<256, 512, 0, stream>>>(xcb, dtv, dAv, ysb);
  k_gate<<<8192, 256, 0, stream>>>(ysb, xcb, zxb, Dp, nw, yb);

  // out_proj + residual: out[8192][1024] = yb[8192][2048] @ w2b[1024][2048]^T + x
  k_gemm<0><<<dim3(64, 8), 256, 0, stream>>>(yb, w2b, 2048, 1024, 1024,
                                             nullptr, out, x, nullptr);

  k_ln<<<8192, 256, 0, stream>>>(out, lw, lb);
}